// Round 1
// 927.562 us; speedup vs baseline: 1.1626x; 1.1626x over previous
//
#include <hip/hip_runtime.h>
#include <hip/hip_bf16.h>
#include <cstdint>

#define E_     16
#define H_     2048
#define I_     768
#define T_     4096
#define TWO_I  1536
#define K2_    (E_ * I_)   // 12288

typedef __bf16 bf16x8 __attribute__((ext_vector_type(8)));
typedef float  floatx4 __attribute__((ext_vector_type(4)));

__device__ __forceinline__ void gload_lds16(const void* g, void* l) {
  __builtin_amdgcn_global_load_lds(
      (const __attribute__((address_space(1))) void*)(void*)g,
      (__attribute__((address_space(3))) void*)l,
      16, 0, 0);
}

#define ASM_VMCNT(n) asm volatile("s_waitcnt vmcnt(" #n ")" ::: "memory")
#define ASM_LGKM0()  asm volatile("s_waitcnt lgkmcnt(0)" ::: "memory")
#define SBAR()       __builtin_amdgcn_s_barrier()
#define SCHED0()     __builtin_amdgcn_sched_barrier(0)

// ---------------- kernel 1: fp32 -> bf16 (hidden states) ----------------
__global__ void k_convert(const float* __restrict__ in, __bf16* __restrict__ out) {
  size_t idx = ((size_t)blockIdx.x * blockDim.x + threadIdx.x) * 8;
  float4 a = *(const float4*)(in + idx);
  float4 b = *(const float4*)(in + idx + 4);
  bf16x8 o;
  o[0] = (__bf16)a.x; o[1] = (__bf16)a.y; o[2] = (__bf16)a.z; o[3] = (__bf16)a.w;
  o[4] = (__bf16)b.x; o[5] = (__bf16)b.y; o[6] = (__bf16)b.z; o[7] = (__bf16)b.w;
  *(bf16x8*)(out + idx) = o;
}

// ------------- kernel 2/3: blockwise dequant + transpose ---------------
// src [e][R][C] fp32 -> dst[ e*slab + n'*rowStride + m ] bf16
// If ilvHalf != 0 (gate_up): source col c in [0,2*ilvHalf);
//   h = c>=ilvHalf, i = c - h*ilvHalf, n' = (i>>5)*64 + h*32 + (i&31)
//   so every 64-row group of dst = [32 gate rows | 32 up rows] of same i-range.
__global__ void k_dq_transpose(const float* __restrict__ src, __bf16* __restrict__ dst,
                               const float* __restrict__ scale, int R, int C,
                               size_t slab, size_t rowStride, int ilvHalf) {
  const int e  = blockIdx.z;
  const int n0 = blockIdx.x * 64;   // col block in src
  const int m0 = blockIdx.y * 64;   // row block in src
  __shared__ float tile[64 * 65];   // [n_local][m_local]
  const float s = scale[((size_t)e * (R >> 7) + (m0 >> 7)) * (C >> 7) + (n0 >> 7)];
  const float* sp = src + ((size_t)e * R + m0) * C + n0;
  const int t  = threadIdx.x;
  const int c4 = (t & 15) * 4;
  const int rb = t >> 4;
  #pragma unroll
  for (int p = 0; p < 4; ++p) {
    int r = p * 16 + rb;
    float4 v = *(const float4*)(sp + (size_t)r * C + c4);
    tile[(c4 + 0) * 65 + r] = v.x * s;
    tile[(c4 + 1) * 65 + r] = v.y * s;
    tile[(c4 + 2) * 65 + r] = v.z * s;
    tile[(c4 + 3) * 65 + r] = v.w * s;
  }
  __syncthreads();
  const int c8 = (t & 7) * 8;
  const int r0 = t >> 3;            // 0..31
  #pragma unroll
  for (int p = 0; p < 2; ++p) {
    int nr = r0 + p * 32;
    int ng = n0 + nr;
    int np;
    if (ilvHalf) {
      int h = (ng >= ilvHalf) ? 1 : 0;
      int iLoc = ng - h * ilvHalf;
      np = ((iLoc >> 5) << 6) + h * 32 + (iLoc & 31);
    } else {
      np = ng;
    }
    const float* row = &tile[nr * 65 + c8];
    bf16x8 o;
    #pragma unroll
    for (int j = 0; j < 8; ++j) o[j] = (__bf16)row[j];
    *(bf16x8*)(dst + (size_t)e * slab + (size_t)np * rowStride + m0 + c8) = o;
  }
}

// ================= 256x256 / BK=64 / 8-wave / 8-phase GEMM =================
// LDS: A,B tiles 256x64 bf16 each, as 2 halves of [128][64], double-buffered.
// Swizzle: element (row, kc-chunk of 8 bf16) stored at chunk slot kc^(row&7)
//   (linear global_load_lds dest + inverse-swizzled global source; reads XOR).
// Stage schedule (tile tau): B at tile tau-2 phases 3,4 (B-buf free after its
//   phase-1 reads); A at tile tau-1 phases 1,2 (other A buffer).
// Checkpoint once per tile: vmcnt(4) -> exactly B(t+2)'s 4 loads outstanding.

#define STG_A(tt, h) do { int b_ = ((tt)&1)*16384 + (h)*8192; \
    gload_lds16(aSrc + (size_t)((h)*128)*LDK + (tt)*64, dA + b_); \
    gload_lds16(aSrc + (size_t)((h)*128 + 64)*LDK + (tt)*64, dA + b_ + 4096); } while (0)
#define STG_B(tt, h) do { int b_ = ((tt)&1)*16384 + (h)*8192; \
    gload_lds16(bSrc + (size_t)((h)*128)*LDK + (tt)*64, dB + b_); \
    gload_lds16(bSrc + (size_t)((h)*128 + 64)*LDK + (tt)*64, dB + b_ + 4096); } while (0)

#define AF4(MI0) do { \
    af[0][0] = *(const bf16x8*)(pA + (MI0)*1024 + kc0); \
    af[0][1] = *(const bf16x8*)(pA + (MI0)*1024 + kc1); \
    af[1][0] = *(const bf16x8*)(pA + ((MI0)+1)*1024 + kc0); \
    af[1][1] = *(const bf16x8*)(pA + ((MI0)+1)*1024 + kc1); } while (0)

#define MFMA16(MI0) do { \
    _Pragma("unroll") \
    for (int ii = 0; ii < 2; ++ii) { \
      _Pragma("unroll") \
      for (int ni = 0; ni < 4; ++ni) { \
        acc[(MI0)+ii][ni] = __builtin_amdgcn_mfma_f32_16x16x32_bf16(af[ii][0], bb[ni][0], acc[(MI0)+ii][ni], 0, 0, 0); \
        acc[(MI0)+ii][ni] = __builtin_amdgcn_mfma_f32_16x16x32_bf16(af[ii][1], bb[ni][1], acc[(MI0)+ii][ni], 0, 0, 0); \
      } \
    } } while (0)

#define PHASE(MI0, STAGE_STMT, CKPT_STMT) do { \
    AF4(MI0); \
    STAGE_STMT; \
    CKPT_STMT; \
    SBAR(); \
    ASM_LGKM0(); \
    SCHED0(); \
    __builtin_amdgcn_s_setprio(1); \
    MFMA16(MI0); \
    __builtin_amdgcn_s_setprio(0); \
    SBAR(); \
  } while (0)

// ---------------- kernel 4: per-expert GEMM1 + SiLU + rw ----------------
// A [T,H] bf16 ; W [E,1536,H] bf16 (gate/up interleaved at 32-row granularity)
// inter [T, E*I] bf16
__global__ __launch_bounds__(512, 2)
void k_gemm1(const __bf16* __restrict__ A, const __bf16* __restrict__ W,
             const float* __restrict__ rw, __bf16* __restrict__ inter) {
  extern __shared__ __align__(16) __bf16 smem[];
  __bf16* sA = smem;              // 32768 elems (64 KiB)
  __bf16* sB = smem + 32768;      // 32768 elems (64 KiB)
  float*  sRW = (float*)(smem + 65536);  // 256 floats

  const int e  = blockIdx.z;
  const int m0 = blockIdx.x * 256;
  const int by = blockIdx.y;
  const int n0 = by * 256;
  const int t    = threadIdx.x;
  const int wave = t >> 6, lane = t & 63;
  const int wm = wave >> 2, wn = wave & 3;
  const int l4 = lane >> 4, r16 = lane & 15;
  const int LDK = H_;

  if (t < 256) sRW[t] = rw[(size_t)(m0 + t) * E_ + e];
  ASM_VMCNT(0);   // drain rw load so stage-load vmcnt accounting is exact

  const int rowSt = t >> 3;
  const int kcSt  = ((t & 7) ^ ((t >> 3) & 7)) << 3;   // inverse swizzle on source
  const __bf16* aSrc = A + (size_t)(m0 + rowSt) * H_ + kcSt;
  const __bf16* bSrc = W + ((size_t)e * TWO_I + n0 + rowSt) * H_ + kcSt;
  __bf16* dA = sA + wave * 512;
  __bf16* dB = sB + wave * 512;

  const int kc0 = (l4 ^ (r16 & 7)) << 3;
  const int kc1 = ((4 + l4) ^ (r16 & 7)) << 3;
  const __bf16* pArd = sA + wm * 8192 + r16 * 64;
  const __bf16* pBrd = sB + (wn >> 1) * 8192 + ((wn & 1) * 64 + r16) * 64;

  floatx4 acc[8][4];
  #pragma unroll
  for (int mi = 0; mi < 8; ++mi)
    #pragma unroll
    for (int ni = 0; ni < 4; ++ni) {
      floatx4 z = {0.f, 0.f, 0.f, 0.f};
      acc[mi][ni] = z;
    }

  // prologue: B(0), A(0), B(1); vmcnt(4) leaves B(1)'s 4 loads in flight
  STG_B(0, 0); STG_B(0, 1); STG_A(0, 0); STG_A(0, 1);
  STG_B(1, 0); STG_B(1, 1);
  ASM_VMCNT(4);
  SBAR();

  const int NT = H_ / 64;   // 32
  for (int tt = 0; tt < NT; ++tt) {
    const int bo = (tt & 1) * 16384;
    const __bf16* pA = pArd + bo;
    const __bf16* pB = pBrd + bo;
    bf16x8 bb[4][2], af[2][2];
    #pragma unroll
    for (int ni = 0; ni < 4; ++ni) {
      bb[ni][0] = *(const bf16x8*)(pB + ni * 1024 + kc0);
      bb[ni][1] = *(const bf16x8*)(pB + ni * 1024 + kc1);
    }
    PHASE(0, if (tt + 1 < NT) STG_A(tt + 1, 0), (void)0);
    PHASE(2, if (tt + 1 < NT) STG_A(tt + 1, 1), (void)0);
    PHASE(4, if (tt + 2 < NT) STG_B(tt + 2, 0), (void)0);
    PHASE(6, if (tt + 2 < NT) STG_B(tt + 2, 1),
             if (tt + 2 < NT) { ASM_VMCNT(4); } else { ASM_VMCNT(0); });
  }

  // epilogue: ni in {0,1} = gate rows, ni+2 = up rows of the SAME i-range
  const int rq = l4 * 4;
  const int gBase = (by * 4 + wn) * 32;
  #pragma unroll
  for (int mi = 0; mi < 8; ++mi) {
    const int rl = wm * 128 + mi * 16 + rq;
    #pragma unroll
    for (int ni = 0; ni < 2; ++ni) {
      const size_t colIdx = (size_t)e * I_ + gBase + ni * 16 + r16;
      #pragma unroll
      for (int r = 0; r < 4; ++r) {
        float g = acc[mi][ni][r];
        float u = acc[mi][ni + 2][r];
        float sil = g / (1.0f + __expf(-g));
        float val = u * sil * sRW[rl + r];
        inter[(size_t)(m0 + rl + r) * K2_ + colIdx] = (__bf16)val;
      }
    }
  }
}

// -------- kernel 5: flat GEMM2, K = E*I, split-K=2, atomic fp32 out ------
// Ainter [T,K2] bf16 ; W [H,K2] bf16 (flat B^T) ; out [T,H] fp32 (pre-zeroed)
__global__ __launch_bounds__(512, 2)
void k_gemm2(const __bf16* __restrict__ Ainter, const __bf16* __restrict__ W,
             float* __restrict__ out) {
  extern __shared__ __align__(16) __bf16 smem[];
  __bf16* sA = smem;
  __bf16* sB = smem + 32768;

  const int m0 = blockIdx.x * 256;
  const int n0 = blockIdx.y * 256;
  const size_t kOff = (size_t)blockIdx.z * (K2_ / 2);   // 6144
  const int t    = threadIdx.x;
  const int wave = t >> 6, lane = t & 63;
  const int wm = wave >> 2, wn = wave & 3;
  const int l4 = lane >> 4, r16 = lane & 15;
  const int LDK = K2_;

  const int rowSt = t >> 3;
  const int kcSt  = ((t & 7) ^ ((t >> 3) & 7)) << 3;
  const __bf16* aSrc = Ainter + (size_t)(m0 + rowSt) * K2_ + kOff + kcSt;
  const __bf16* bSrc = W      + (size_t)(n0 + rowSt) * K2_ + kOff + kcSt;
  __bf16* dA = sA + wave * 512;
  __bf16* dB = sB + wave * 512;

  const int kc0 = (l4 ^ (r16 & 7)) << 3;
  const int kc1 = ((4 + l4) ^ (r16 & 7)) << 3;
  const __bf16* pArd = sA + wm * 8192 + r16 * 64;
  const __bf16* pBrd = sB + (wn >> 1) * 8192 + ((wn & 1) * 64 + r16) * 64;

  floatx4 acc[8][4];
  #pragma unroll
  for (int mi = 0; mi < 8; ++mi)
    #pragma unroll
    for (int ni = 0; ni < 4; ++ni) {
      floatx4 z = {0.f, 0.f, 0.f, 0.f};
      acc[mi][ni] = z;
    }

  STG_B(0, 0); STG_B(0, 1); STG_A(0, 0); STG_A(0, 1);
  STG_B(1, 0); STG_B(1, 1);
  ASM_VMCNT(4);
  SBAR();

  const int NT = (K2_ / 2) / 64;   // 96
  for (int tt = 0; tt < NT; ++tt) {
    const int bo = (tt & 1) * 16384;
    const __bf16* pA = pArd + bo;
    const __bf16* pB = pBrd + bo;
    bf16x8 bb[4][2], af[2][2];
    #pragma unroll
    for (int ni = 0; ni < 4; ++ni) {
      bb[ni][0] = *(const bf16x8*)(pB + ni * 1024 + kc0);
      bb[ni][1] = *(const bf16x8*)(pB + ni * 1024 + kc1);
    }
    PHASE(0, if (tt + 1 < NT) STG_A(tt + 1, 0), (void)0);
    PHASE(2, if (tt + 1 < NT) STG_A(tt + 1, 1), (void)0);
    PHASE(4, if (tt + 2 < NT) STG_B(tt + 2, 0), (void)0);
    PHASE(6, if (tt + 2 < NT) STG_B(tt + 2, 1),
             if (tt + 2 < NT) { ASM_VMCNT(4); } else { ASM_VMCNT(0); });
  }

  const int rq = l4 * 4;
  #pragma unroll
  for (int mi = 0; mi < 8; ++mi) {
    const int rl = wm * 128 + mi * 16 + rq;
    #pragma unroll
    for (int ni = 0; ni < 4; ++ni) {
      const int cl = wn * 64 + ni * 16 + r16;
      #pragma unroll
      for (int r = 0; r < 4; ++r)
        unsafeAtomicAdd(out + (size_t)(m0 + rl + r) * H_ + n0 + cl, acc[mi][ni][r]);
    }
  }
}

extern "C" void kernel_launch(void* const* d_in, const int* in_sizes, int n_in,
                              void* d_out, int out_size, void* d_ws, size_t ws_size,
                              hipStream_t stream) {
  const float* hs   = (const float*)d_in[0];   // [B,S,H]
  const float* rw   = (const float*)d_in[1];   // [T,E]
  const float* gup  = (const float*)d_in[2];   // [E,H,2I]
  const float* gups = (const float*)d_in[3];   // [E,H/128,2I/128]
  const float* dnp  = (const float*)d_in[4];   // [E,I,H]
  const float* dnps = (const float*)d_in[5];   // [E,I/128,H/128]
  float* out = (float*)d_out;                  // [T,H] fp32

  char* ws = (char*)d_ws;
  __bf16* hsb  = (__bf16*)ws;                          // 16 MiB: [T,H]
  __bf16* wgu  = (__bf16*)(ws + (size_t)(16 << 20));   // 96 MiB: [E,1536,H] interleaved
  __bf16* wdn  = (__bf16*)(ws + (size_t)(112 << 20));  // 48 MiB: [H, E*I] flat B^T
  __bf16* intr = (__bf16*)(ws + (size_t)(160 << 20));  // 96 MiB: [T, E*I]

  static int inited = 0;
  if (!inited) {
    hipFuncSetAttribute((const void*)k_gemm1,
                        hipFuncAttributeMaxDynamicSharedMemorySize, 132096);
    hipFuncSetAttribute((const void*)k_gemm2,
                        hipFuncAttributeMaxDynamicSharedMemorySize, 131072);
    inited = 1;
  }

  hipMemsetAsync(out, 0, (size_t)T_ * H_ * sizeof(float), stream);

  k_convert<<<(T_ * H_) / (256 * 8), 256, 0, stream>>>(hs, hsb);
  k_dq_transpose<<<dim3(TWO_I / 64, H_ / 64, E_), 256, 0, stream>>>(
      gup, wgu, gups, H_, TWO_I, (size_t)TWO_I * H_, (size_t)H_, I_);
  k_dq_transpose<<<dim3(H_ / 64, I_ / 64, E_), 256, 0, stream>>>(
      dnp, wdn, dnps, I_, H_, (size_t)I_, (size_t)K2_, 0);
  k_gemm1<<<dim3(T_ / 256, TWO_I / 256, E_), 512, 132096, stream>>>(hsb, wgu, rw, intr);
  k_gemm2<<<dim3(T_ / 256, H_ / 256, 2), 512, 131072, stream>>>(intr, wdn, out);
}

// Round 2
// 920.316 us; speedup vs baseline: 1.1718x; 1.0079x over previous
//
#include <hip/hip_runtime.h>
#include <hip/hip_bf16.h>
#include <cstdint>

#define E_     16
#define H_     2048
#define I_     768
#define T_     4096
#define TWO_I  1536
#define K2_    (E_ * I_)   // 12288

typedef __bf16 bf16x8 __attribute__((ext_vector_type(8)));
typedef float  floatx4 __attribute__((ext_vector_type(4)));

__device__ __forceinline__ void gload_lds16(const void* g, void* l) {
  __builtin_amdgcn_global_load_lds(
      (const __attribute__((address_space(1))) void*)(void*)g,
      (__attribute__((address_space(3))) void*)l,
      16, 0, 0);
}

#define ASM_VMCNT(n) asm volatile("s_waitcnt vmcnt(" #n ")" ::: "memory")
#define ASM_LGKM0()  asm volatile("s_waitcnt lgkmcnt(0)" ::: "memory")
#define SBAR()       __builtin_amdgcn_s_barrier()
#define SCHED0()     __builtin_amdgcn_sched_barrier(0)

// ---------------- kernel 1: fp32 -> bf16 (hidden states) ----------------
__global__ void k_convert(const float* __restrict__ in, __bf16* __restrict__ out) {
  size_t idx = ((size_t)blockIdx.x * blockDim.x + threadIdx.x) * 8;
  float4 a = *(const float4*)(in + idx);
  float4 b = *(const float4*)(in + idx + 4);
  bf16x8 o;
  o[0] = (__bf16)a.x; o[1] = (__bf16)a.y; o[2] = (__bf16)a.z; o[3] = (__bf16)a.w;
  o[4] = (__bf16)b.x; o[5] = (__bf16)b.y; o[6] = (__bf16)b.z; o[7] = (__bf16)b.w;
  *(bf16x8*)(out + idx) = o;
}

// ------------- kernel 2/3: blockwise dequant + transpose ---------------
__global__ void k_dq_transpose(const float* __restrict__ src, __bf16* __restrict__ dst,
                               const float* __restrict__ scale, int R, int C,
                               size_t slab, size_t rowStride, int ilvHalf) {
  const int e  = blockIdx.z;
  const int n0 = blockIdx.x * 64;   // col block in src
  const int m0 = blockIdx.y * 64;   // row block in src
  __shared__ float tile[64 * 65];   // [n_local][m_local]
  const float s = scale[((size_t)e * (R >> 7) + (m0 >> 7)) * (C >> 7) + (n0 >> 7)];
  const float* sp = src + ((size_t)e * R + m0) * C + n0;
  const int t  = threadIdx.x;
  const int c4 = (t & 15) * 4;
  const int rb = t >> 4;
  #pragma unroll
  for (int p = 0; p < 4; ++p) {
    int r = p * 16 + rb;
    float4 v = *(const float4*)(sp + (size_t)r * C + c4);
    tile[(c4 + 0) * 65 + r] = v.x * s;
    tile[(c4 + 1) * 65 + r] = v.y * s;
    tile[(c4 + 2) * 65 + r] = v.z * s;
    tile[(c4 + 3) * 65 + r] = v.w * s;
  }
  __syncthreads();
  const int c8 = (t & 7) * 8;
  const int r0 = t >> 3;            // 0..31
  #pragma unroll
  for (int p = 0; p < 2; ++p) {
    int nr = r0 + p * 32;
    int ng = n0 + nr;
    int np;
    if (ilvHalf) {
      int h = (ng >= ilvHalf) ? 1 : 0;
      int iLoc = ng - h * ilvHalf;
      np = ((iLoc >> 5) << 6) + h * 32 + (iLoc & 31);
    } else {
      np = ng;
    }
    const float* row = &tile[nr * 65 + c8];
    bf16x8 o;
    #pragma unroll
    for (int j = 0; j < 8; ++j) o[j] = (__bf16)row[j];
    *(bf16x8*)(dst + (size_t)e * slab + (size_t)np * rowStride + m0 + c8) = o;
  }
}

// ================= 256x256 / BK=64 / 8-wave / 8-phase GEMM =================
#define STG_A(tt, h) do { int b_ = ((tt)&1)*16384 + (h)*8192; \
    gload_lds16(aSrc + (size_t)((h)*128)*LDK + (tt)*64, dA + b_); \
    gload_lds16(aSrc + (size_t)((h)*128 + 64)*LDK + (tt)*64, dA + b_ + 4096); } while (0)
#define STG_B(tt, h) do { int b_ = ((tt)&1)*16384 + (h)*8192; \
    gload_lds16(bSrc + (size_t)((h)*128)*LDK + (tt)*64, dB + b_); \
    gload_lds16(bSrc + (size_t)((h)*128 + 64)*LDK + (tt)*64, dB + b_ + 4096); } while (0)

#define AF4(MI0) do { \
    af[0][0] = *(const bf16x8*)(pA + (MI0)*1024 + kc0); \
    af[0][1] = *(const bf16x8*)(pA + (MI0)*1024 + kc1); \
    af[1][0] = *(const bf16x8*)(pA + ((MI0)+1)*1024 + kc0); \
    af[1][1] = *(const bf16x8*)(pA + ((MI0)+1)*1024 + kc1); } while (0)

#define MFMA16(MI0) do { \
    _Pragma("unroll") \
    for (int ii = 0; ii < 2; ++ii) { \
      _Pragma("unroll") \
      for (int ni = 0; ni < 4; ++ni) { \
        acc[(MI0)+ii][ni] = __builtin_amdgcn_mfma_f32_16x16x32_bf16(af[ii][0], bb[ni][0], acc[(MI0)+ii][ni], 0, 0, 0); \
        acc[(MI0)+ii][ni] = __builtin_amdgcn_mfma_f32_16x16x32_bf16(af[ii][1], bb[ni][1], acc[(MI0)+ii][ni], 0, 0, 0); \
      } \
    } } while (0)

#define PHASE(MI0, STAGE_STMT, CKPT_STMT) do { \
    AF4(MI0); \
    STAGE_STMT; \
    CKPT_STMT; \
    SBAR(); \
    ASM_LGKM0(); \
    SCHED0(); \
    __builtin_amdgcn_s_setprio(1); \
    MFMA16(MI0); \
    __builtin_amdgcn_s_setprio(0); \
    SBAR(); \
  } while (0)

// ---------------- kernel 4: per-expert GEMM1 + SiLU + rw ----------------
// Grid (16,6,16) flattened + XCD-swizzled: each XCD owns a contiguous
// 192-block chunk (= 2 experts), decomposed m-fastest so 16 m-blocks
// reuse each 1 MB B-panel inside one 4 MB L2.
__global__ __launch_bounds__(512, 2)
void k_gemm1(const __bf16* __restrict__ A, const __bf16* __restrict__ W,
             const float* __restrict__ rw, __bf16* __restrict__ inter) {
  extern __shared__ __align__(16) __bf16 smem[];
  __bf16* sA = smem;              // 32768 elems (64 KiB)
  __bf16* sB = smem + 32768;      // 32768 elems (64 KiB)
  float*  sRW = (float*)(smem + 65536);  // 256 floats

  const int lid = blockIdx.x + 16 * (blockIdx.y + 6 * blockIdx.z);  // 0..1535
  const int nid = (lid & 7) * 192 + (lid >> 3);                     // bijective
  const int e  = nid / 96;
  const int r_ = nid - e * 96;
  const int by = r_ >> 4;           // n-block 0..5
  const int m0 = (r_ & 15) * 256;
  const int n0 = by * 256;

  const int t    = threadIdx.x;
  const int wave = t >> 6, lane = t & 63;
  const int wm = wave >> 2, wn = wave & 3;
  const int l4 = lane >> 4, r16 = lane & 15;
  const int LDK = H_;

  if (t < 256) sRW[t] = rw[(size_t)(m0 + t) * E_ + e];
  ASM_VMCNT(0);   // drain rw load so stage-load vmcnt accounting is exact

  const int rowSt = t >> 3;
  const int kcSt  = ((t & 7) ^ ((t >> 3) & 7)) << 3;   // inverse swizzle on source
  const __bf16* aSrc = A + (size_t)(m0 + rowSt) * H_ + kcSt;
  const __bf16* bSrc = W + ((size_t)e * TWO_I + n0 + rowSt) * H_ + kcSt;
  __bf16* dA = sA + wave * 512;
  __bf16* dB = sB + wave * 512;

  const int kc0 = (l4 ^ (r16 & 7)) << 3;
  const int kc1 = ((4 + l4) ^ (r16 & 7)) << 3;
  const __bf16* pArd = sA + wm * 8192 + r16 * 64;
  const __bf16* pBrd = sB + (wn >> 1) * 8192 + ((wn & 1) * 64 + r16) * 64;

  floatx4 acc[8][4];
  #pragma unroll
  for (int mi = 0; mi < 8; ++mi)
    #pragma unroll
    for (int ni = 0; ni < 4; ++ni) {
      floatx4 z = {0.f, 0.f, 0.f, 0.f};
      acc[mi][ni] = z;
    }

  STG_B(0, 0); STG_B(0, 1); STG_A(0, 0); STG_A(0, 1);
  STG_B(1, 0); STG_B(1, 1);
  ASM_VMCNT(4);
  SBAR();

  const int NT = H_ / 64;   // 32
  for (int tt = 0; tt < NT; ++tt) {
    const int bo = (tt & 1) * 16384;
    const __bf16* pA = pArd + bo;
    const __bf16* pB = pBrd + bo;
    bf16x8 bb[4][2], af[2][2];
    #pragma unroll
    for (int ni = 0; ni < 4; ++ni) {
      bb[ni][0] = *(const bf16x8*)(pB + ni * 1024 + kc0);
      bb[ni][1] = *(const bf16x8*)(pB + ni * 1024 + kc1);
    }
    PHASE(0, if (tt + 1 < NT) STG_A(tt + 1, 0), (void)0);
    PHASE(2, if (tt + 1 < NT) STG_A(tt + 1, 1), (void)0);
    PHASE(4, if (tt + 2 < NT) STG_B(tt + 2, 0), (void)0);
    PHASE(6, if (tt + 2 < NT) STG_B(tt + 2, 1),
             if (tt + 2 < NT) { ASM_VMCNT(4); } else { ASM_VMCNT(0); });
  }

  // epilogue: ni in {0,1} = gate rows, ni+2 = up rows of the SAME i-range
  const int rq = l4 * 4;
  const int gBase = (by * 4 + wn) * 32;
  #pragma unroll
  for (int mi = 0; mi < 8; ++mi) {
    const int rl = wm * 128 + mi * 16 + rq;
    #pragma unroll
    for (int ni = 0; ni < 2; ++ni) {
      const size_t colIdx = (size_t)e * I_ + gBase + ni * 16 + r16;
      #pragma unroll
      for (int r = 0; r < 4; ++r) {
        float g = acc[mi][ni][r];
        float u = acc[mi][ni + 2][r];
        float sil = g / (1.0f + __expf(-g));
        float val = u * sil * sRW[rl + r];
        inter[(size_t)(m0 + rl + r) * K2_ + colIdx] = (__bf16)val;
      }
    }
  }
}

// -------- kernel 5: flat GEMM2, K = E*I, split-K=2, two buffers ----------
// z-half 0 -> out, z-half 1 -> part (plain coalesced stores, no atomics).
// XCD swizzle: each XCD owns 32 contiguous blocks = 2 B-panels (3 MB each,
// L2-resident) x 16 m-blocks.
__global__ __launch_bounds__(512, 2)
void k_gemm2(const __bf16* __restrict__ Ainter, const __bf16* __restrict__ W,
             float* __restrict__ out0, float* __restrict__ out1) {
  extern __shared__ __align__(16) __bf16 smem[];
  __bf16* sA = smem;
  __bf16* sB = smem + 32768;

  const int lid = blockIdx.x + 16 * (blockIdx.y + 8 * blockIdx.z);  // 0..255
  const int nid = (lid & 7) * 32 + (lid >> 3);
  const int bz = nid >> 7;          // k-half
  const int r_ = nid & 127;
  const int n0 = (r_ >> 4) * 256;
  const int m0 = (r_ & 15) * 256;
  float* dst = bz ? out1 : out0;
  const size_t kOff = (size_t)bz * (K2_ / 2);   // 6144

  const int t    = threadIdx.x;
  const int wave = t >> 6, lane = t & 63;
  const int wm = wave >> 2, wn = wave & 3;
  const int l4 = lane >> 4, r16 = lane & 15;
  const int LDK = K2_;

  const int rowSt = t >> 3;
  const int kcSt  = ((t & 7) ^ ((t >> 3) & 7)) << 3;
  const __bf16* aSrc = Ainter + (size_t)(m0 + rowSt) * K2_ + kOff + kcSt;
  const __bf16* bSrc = W      + (size_t)(n0 + rowSt) * K2_ + kOff + kcSt;
  __bf16* dA = sA + wave * 512;
  __bf16* dB = sB + wave * 512;

  const int kc0 = (l4 ^ (r16 & 7)) << 3;
  const int kc1 = ((4 + l4) ^ (r16 & 7)) << 3;
  const __bf16* pArd = sA + wm * 8192 + r16 * 64;
  const __bf16* pBrd = sB + (wn >> 1) * 8192 + ((wn & 1) * 64 + r16) * 64;

  floatx4 acc[8][4];
  #pragma unroll
  for (int mi = 0; mi < 8; ++mi)
    #pragma unroll
    for (int ni = 0; ni < 4; ++ni) {
      floatx4 z = {0.f, 0.f, 0.f, 0.f};
      acc[mi][ni] = z;
    }

  STG_B(0, 0); STG_B(0, 1); STG_A(0, 0); STG_A(0, 1);
  STG_B(1, 0); STG_B(1, 1);
  ASM_VMCNT(4);
  SBAR();

  const int NT = (K2_ / 2) / 64;   // 96
  for (int tt = 0; tt < NT; ++tt) {
    const int bo = (tt & 1) * 16384;
    const __bf16* pA = pArd + bo;
    const __bf16* pB = pBrd + bo;
    bf16x8 bb[4][2], af[2][2];
    #pragma unroll
    for (int ni = 0; ni < 4; ++ni) {
      bb[ni][0] = *(const bf16x8*)(pB + ni * 1024 + kc0);
      bb[ni][1] = *(const bf16x8*)(pB + ni * 1024 + kc1);
    }
    PHASE(0, if (tt + 1 < NT) STG_A(tt + 1, 0), (void)0);
    PHASE(2, if (tt + 1 < NT) STG_A(tt + 1, 1), (void)0);
    PHASE(4, if (tt + 2 < NT) STG_B(tt + 2, 0), (void)0);
    PHASE(6, if (tt + 2 < NT) STG_B(tt + 2, 1),
             if (tt + 2 < NT) { ASM_VMCNT(4); } else { ASM_VMCNT(0); });
  }

  const int rq = l4 * 4;
  #pragma unroll
  for (int mi = 0; mi < 8; ++mi) {
    const int rl = wm * 128 + mi * 16 + rq;
    #pragma unroll
    for (int ni = 0; ni < 4; ++ni) {
      const int cl = wn * 64 + ni * 16 + r16;
      #pragma unroll
      for (int r = 0; r < 4; ++r)
        dst[(size_t)(m0 + rl + r) * H_ + n0 + cl] = acc[mi][ni][r];
    }
  }
}

// -------- kernel 6: out += part (split-K reduction) ----------------------
__global__ void k_addout(float* __restrict__ out, const float* __restrict__ part) {
  size_t i = ((size_t)blockIdx.x * blockDim.x + threadIdx.x) * 4;
  float4 a = *(const float4*)(out + i);
  float4 b = *(const float4*)(part + i);
  a.x += b.x; a.y += b.y; a.z += b.z; a.w += b.w;
  *(float4*)(out + i) = a;
}

extern "C" void kernel_launch(void* const* d_in, const int* in_sizes, int n_in,
                              void* d_out, int out_size, void* d_ws, size_t ws_size,
                              hipStream_t stream) {
  const float* hs   = (const float*)d_in[0];   // [B,S,H]
  const float* rw   = (const float*)d_in[1];   // [T,E]
  const float* gup  = (const float*)d_in[2];   // [E,H,2I]
  const float* gups = (const float*)d_in[3];   // [E,H/128,2I/128]
  const float* dnp  = (const float*)d_in[4];   // [E,I,H]
  const float* dnps = (const float*)d_in[5];   // [E,I/128,H/128]
  float* out = (float*)d_out;                  // [T,H] fp32

  char* ws = (char*)d_ws;
  __bf16* hsb  = (__bf16*)ws;                          // 16 MiB: [T,H]
  __bf16* wgu  = (__bf16*)(ws + (size_t)(16 << 20));   // 96 MiB: [E,1536,H] interleaved
  __bf16* wdn  = (__bf16*)(ws + (size_t)(112 << 20));  // 48 MiB: [H, E*I] flat B^T
  __bf16* intr = (__bf16*)(ws + (size_t)(160 << 20));  // 96 MiB: [T, E*I]
  // part reuses the wgu region (dead after k_gemm1): 32 MiB fp32 [T,H]
  float* part = (float*)(ws + (size_t)(16 << 20));

  static int inited = 0;
  if (!inited) {
    hipFuncSetAttribute((const void*)k_gemm1,
                        hipFuncAttributeMaxDynamicSharedMemorySize, 132096);
    hipFuncSetAttribute((const void*)k_gemm2,
                        hipFuncAttributeMaxDynamicSharedMemorySize, 131072);
    inited = 1;
  }

  k_convert<<<(T_ * H_) / (256 * 8), 256, 0, stream>>>(hs, hsb);
  k_dq_transpose<<<dim3(TWO_I / 64, H_ / 64, E_), 256, 0, stream>>>(
      gup, wgu, gups, H_, TWO_I, (size_t)TWO_I * H_, (size_t)H_, I_);
  k_dq_transpose<<<dim3(H_ / 64, I_ / 64, E_), 256, 0, stream>>>(
      dnp, wdn, dnps, I_, H_, (size_t)I_, (size_t)K2_, 0);
  k_gemm1<<<dim3(T_ / 256, TWO_I / 256, E_), 512, 132096, stream>>>(hsb, wgu, rw, intr);
  k_gemm2<<<dim3(T_ / 256, H_ / 256, 2), 512, 131072, stream>>>(intr, wdn, out, part);
  k_addout<<<(T_ * H_) / (256 * 4), 256, 0, stream>>>(out, part);
}

// Round 4
// 918.667 us; speedup vs baseline: 1.1739x; 1.0018x over previous
//
#include <hip/hip_runtime.h>
#include <hip/hip_bf16.h>
#include <cstdint>

#define E_     16
#define H_     2048
#define I_     768
#define T_     4096
#define TWO_I  1536
#define K2_    (E_ * I_)   // 12288

typedef __bf16 bf16x8 __attribute__((ext_vector_type(8)));
typedef float  floatx4 __attribute__((ext_vector_type(4)));

__device__ __forceinline__ void gload_lds16(const void* g, void* l) {
  __builtin_amdgcn_global_load_lds(
      (const __attribute__((address_space(1))) void*)(void*)g,
      (__attribute__((address_space(3))) void*)l,
      16, 0, 0);
}

#define ASM_VMCNT(n) asm volatile("s_waitcnt vmcnt(" #n ")" ::: "memory")
#define ASM_LGKM(n)  asm volatile("s_waitcnt lgkmcnt(" #n ")" ::: "memory")
#define SBAR()       __builtin_amdgcn_s_barrier()
#define SCHED0()     __builtin_amdgcn_sched_barrier(0)
#define PRIO1()      __builtin_amdgcn_s_setprio(1)
#define PRIO0()      __builtin_amdgcn_s_setprio(0)

// ------------- kernel 1: fused convert + blockwise dequant/transpose -----
__device__ __forceinline__ void dq_body(const float* __restrict__ src,
                                        __bf16* __restrict__ dst,
                                        const float* __restrict__ scale,
                                        int e, int n0, int m0, int R, int C,
                                        size_t slab, size_t rowStride, int ilvHalf,
                                        float* tile) {
  const float s = scale[((size_t)e * (R >> 7) + (m0 >> 7)) * (C >> 7) + (n0 >> 7)];
  const float* sp = src + ((size_t)e * R + m0) * C + n0;
  const int t  = threadIdx.x;
  const int c4 = (t & 15) * 4;
  const int rb = t >> 4;
  #pragma unroll
  for (int p = 0; p < 4; ++p) {
    int r = p * 16 + rb;
    float4 v = *(const float4*)(sp + (size_t)r * C + c4);
    tile[(c4 + 0) * 65 + r] = v.x * s;
    tile[(c4 + 1) * 65 + r] = v.y * s;
    tile[(c4 + 2) * 65 + r] = v.z * s;
    tile[(c4 + 3) * 65 + r] = v.w * s;
  }
  __syncthreads();
  const int c8 = (t & 7) * 8;
  const int r0 = t >> 3;            // 0..31
  #pragma unroll
  for (int p = 0; p < 2; ++p) {
    int nr = r0 + p * 32;
    int ng = n0 + nr;
    int np;
    if (ilvHalf) {
      int h = (ng >= ilvHalf) ? 1 : 0;
      int iLoc = ng - h * ilvHalf;
      np = ((iLoc >> 5) << 6) + h * 32 + (iLoc & 31);
    } else {
      np = ng;
    }
    const float* row = &tile[nr * 65 + c8];
    bf16x8 o;
    #pragma unroll
    for (int j = 0; j < 8; ++j) o[j] = (__bf16)row[j];
    *(bf16x8*)(dst + (size_t)e * slab + (size_t)np * rowStride + m0 + c8) = o;
  }
}

__global__ void k_prep(const float* __restrict__ hs, __bf16* __restrict__ hsb,
                       const float* __restrict__ gup, __bf16* __restrict__ wgu,
                       const float* __restrict__ gups,
                       const float* __restrict__ dnp, __bf16* __restrict__ wdn,
                       const float* __restrict__ dnps) {
  __shared__ float tile[64 * 65];
  const int id = blockIdx.x;
  if (id < 4096) {
    size_t idx = ((size_t)id * blockDim.x + threadIdx.x) * 8;
    float4 a = *(const float4*)(hs + idx);
    float4 b = *(const float4*)(hs + idx + 4);
    bf16x8 o;
    o[0] = (__bf16)a.x; o[1] = (__bf16)a.y; o[2] = (__bf16)a.z; o[3] = (__bf16)a.w;
    o[4] = (__bf16)b.x; o[5] = (__bf16)b.y; o[6] = (__bf16)b.z; o[7] = (__bf16)b.w;
    *(bf16x8*)(hsb + idx) = o;
  } else if (id < 4096 + 12288) {
    const int id2 = id - 4096;
    const int bx = id2 % 24;
    const int rest = id2 / 24;
    const int by = rest & 31;
    const int e  = rest >> 5;
    dq_body(gup, wgu, gups, e, bx * 64, by * 64, H_, TWO_I,
            (size_t)TWO_I * H_, (size_t)H_, I_, tile);
  } else {
    const int id3 = id - (4096 + 12288);
    const int bx = id3 & 31;
    const int rest = id3 >> 5;
    const int by = rest % 12;
    const int e  = rest / 12;
    dq_body(dnp, wdn, dnps, e, bx * 64, by * 64, I_, H_,
            (size_t)I_, (size_t)K2_, 0, tile);
  }
}

// ================= 256x256 / BK=64 / 8-wave / 8-phase GEMM =================
// A-fragment register loads are pipelined ONE PHASE AHEAD (afA/afB ping-pong),
// so the lgkmcnt at each phase entry finds its data already landed.
#define STG_A(tt, h) do { int b_ = ((tt)&1)*16384 + (h)*8192; \
    gload_lds16(aSrc + (size_t)((h)*128)*LDK + (tt)*64, dA + b_); \
    gload_lds16(aSrc + (size_t)((h)*128 + 64)*LDK + (tt)*64, dA + b_ + 4096); } while (0)
#define STG_B(tt, h) do { int b_ = ((tt)&1)*16384 + (h)*8192; \
    gload_lds16(bSrc + (size_t)((h)*128)*LDK + (tt)*64, dB + b_); \
    gload_lds16(bSrc + (size_t)((h)*128 + 64)*LDK + (tt)*64, dB + b_ + 4096); } while (0)

#define AFLD(DST, MI0) do { \
    DST[0][0] = *(const bf16x8*)(pA + (MI0)*1024 + kc0); \
    DST[0][1] = *(const bf16x8*)(pA + (MI0)*1024 + kc1); \
    DST[1][0] = *(const bf16x8*)(pA + ((MI0)+1)*1024 + kc0); \
    DST[1][1] = *(const bf16x8*)(pA + ((MI0)+1)*1024 + kc1); } while (0)

#define BBLD() do { \
    _Pragma("unroll") \
    for (int ni = 0; ni < 4; ++ni) { \
      bb[ni][0] = *(const bf16x8*)(pB + ni * 1024 + kc0); \
      bb[ni][1] = *(const bf16x8*)(pB + ni * 1024 + kc1); \
    } } while (0)

#define MFMA16(MI0, AF) do { \
    _Pragma("unroll") \
    for (int ii = 0; ii < 2; ++ii) { \
      _Pragma("unroll") \
      for (int ni = 0; ni < 4; ++ni) { \
        acc[(MI0)+ii][ni] = __builtin_amdgcn_mfma_f32_16x16x32_bf16(AF[ii][0], bb[ni][0], acc[(MI0)+ii][ni], 0, 0, 0); \
        acc[(MI0)+ii][ni] = __builtin_amdgcn_mfma_f32_16x16x32_bf16(AF[ii][1], bb[ni][1], acc[(MI0)+ii][ni], 0, 0, 0); \
      } \
    } } while (0)

// One K-tile with staging (used for tt in [0, NT-1)):
#define TILE_BODY_STAGED(tt, NT) do { \
    const int bo = ((tt) & 1) * 16384; \
    const __bf16* pA = pArd + bo; \
    const __bf16* pB = pBrd + bo; \
    bf16x8 bb[4][2], afA[2][2], afB[2][2]; \
    BBLD(); \
    AFLD(afA, 0); \
    /* P0 */ \
    AFLD(afB, 2); \
    STG_A((tt) + 1, 0); \
    SBAR(); ASM_LGKM(4); SCHED0(); \
    PRIO1(); MFMA16(0, afA); PRIO0(); SBAR(); \
    /* P1 */ \
    AFLD(afA, 4); \
    STG_A((tt) + 1, 1); \
    SBAR(); ASM_LGKM(4); SCHED0(); \
    PRIO1(); MFMA16(2, afB); PRIO0(); SBAR(); \
    /* P2 */ \
    AFLD(afB, 6); \
    if ((tt) + 2 < (NT)) STG_B((tt) + 2, 0); \
    SBAR(); ASM_LGKM(4); SCHED0(); \
    PRIO1(); MFMA16(4, afA); PRIO0(); SBAR(); \
    /* P3 */ \
    if ((tt) + 2 < (NT)) { STG_B((tt) + 2, 1); ASM_VMCNT(4); } \
    else                 { ASM_VMCNT(0); } \
    SBAR(); ASM_LGKM(0); SCHED0(); \
    PRIO1(); MFMA16(6, afB); PRIO0(); SBAR(); \
  } while (0)

// Peeled last K-tile (no staging, no vm checkpoints):
#define TILE_BODY_LAST(tt) do { \
    const int bo = ((tt) & 1) * 16384; \
    const __bf16* pA = pArd + bo; \
    const __bf16* pB = pBrd + bo; \
    bf16x8 bb[4][2], afA[2][2], afB[2][2]; \
    BBLD(); \
    AFLD(afA, 0); \
    AFLD(afB, 2); \
    SBAR(); ASM_LGKM(4); SCHED0(); \
    PRIO1(); MFMA16(0, afA); PRIO0(); SBAR(); \
    AFLD(afA, 4); \
    SBAR(); ASM_LGKM(4); SCHED0(); \
    PRIO1(); MFMA16(2, afB); PRIO0(); SBAR(); \
    AFLD(afB, 6); \
    SBAR(); ASM_LGKM(4); SCHED0(); \
    PRIO1(); MFMA16(4, afA); PRIO0(); SBAR(); \
    SBAR(); ASM_LGKM(0); SCHED0(); \
    PRIO1(); MFMA16(6, afB); PRIO0(); SBAR(); \
  } while (0)

// ---------------- kernel 4: per-expert GEMM1 + SiLU + rw ----------------
__global__ __launch_bounds__(512, 2)
void k_gemm1(const __bf16* __restrict__ A, const __bf16* __restrict__ W,
             const float* __restrict__ rw, __bf16* __restrict__ inter) {
  extern __shared__ __align__(16) __bf16 smem[];
  __bf16* sA = smem;              // 32768 elems (64 KiB)
  __bf16* sB = smem + 32768;      // 32768 elems (64 KiB)
  float*  sRW = (float*)(smem + 65536);  // 256 floats

  const int lid = blockIdx.x + 16 * (blockIdx.y + 6 * blockIdx.z);  // 0..1535
  const int nid = (lid & 7) * 192 + (lid >> 3);                     // bijective
  const int e  = nid / 96;
  const int r_ = nid - e * 96;
  const int by = r_ >> 4;           // n-block 0..5
  const int m0 = (r_ & 15) * 256;
  const int n0 = by * 256;

  const int t    = threadIdx.x;
  const int wave = t >> 6, lane = t & 63;
  const int wm = wave >> 2, wn = wave & 3;
  const int l4 = lane >> 4, r16 = lane & 15;
  const int LDK = H_;

  if (t < 256) sRW[t] = rw[(size_t)(m0 + t) * E_ + e];

  const int rowSt = t >> 3;
  const int kcSt  = ((t & 7) ^ ((t >> 3) & 7)) << 3;   // inverse swizzle on source
  const __bf16* aSrc = A + (size_t)(m0 + rowSt) * H_ + kcSt;
  const __bf16* bSrc = W + ((size_t)e * TWO_I + n0 + rowSt) * H_ + kcSt;
  __bf16* dA = sA + wave * 512;
  __bf16* dB = sB + wave * 512;

  const int kc0 = (l4 ^ (r16 & 7)) << 3;
  const int kc1 = ((4 + l4) ^ (r16 & 7)) << 3;
  const __bf16* pArd = sA + wm * 8192 + r16 * 64;
  const __bf16* pBrd = sB + (wn >> 1) * 8192 + ((wn & 1) * 64 + r16) * 64;

  floatx4 acc[8][4];
  #pragma unroll
  for (int mi = 0; mi < 8; ++mi)
    #pragma unroll
    for (int ni = 0; ni < 4; ++ni) {
      floatx4 z = {0.f, 0.f, 0.f, 0.f};
      acc[mi][ni] = z;
    }

  // prologue: hard-drain so every wave sees B(0),A(0),B(1) resident at barrier
  STG_B(0, 0); STG_B(0, 1); STG_A(0, 0); STG_A(0, 1);
  STG_B(1, 0); STG_B(1, 1);
  ASM_VMCNT(0);
  SBAR();

  const int NT = H_ / 64;   // 32
  for (int tt = 0; tt < NT - 1; ++tt) {
    TILE_BODY_STAGED(tt, NT);
  }
  TILE_BODY_LAST(NT - 1);

  // epilogue: ni in {0,1} = gate rows, ni+2 = up rows of the SAME i-range
  const int rq = l4 * 4;
  const int gBase = (by * 4 + wn) * 32;
  #pragma unroll
  for (int mi = 0; mi < 8; ++mi) {
    const int rl = wm * 128 + mi * 16 + rq;
    #pragma unroll
    for (int ni = 0; ni < 2; ++ni) {
      const size_t colIdx = (size_t)e * I_ + gBase + ni * 16 + r16;
      #pragma unroll
      for (int r = 0; r < 4; ++r) {
        float g = acc[mi][ni][r];
        float u = acc[mi][ni + 2][r];
        float sil = g / (1.0f + __expf(-g));
        float val = u * sil * sRW[rl + r];
        inter[(size_t)(m0 + rl + r) * K2_ + colIdx] = (__bf16)val;
      }
    }
  }
}

// -------- kernel 5: flat GEMM2, K = E*I, split-K=2, two buffers ----------
__global__ __launch_bounds__(512, 2)
void k_gemm2(const __bf16* __restrict__ Ainter, const __bf16* __restrict__ W,
             float* __restrict__ out0, float* __restrict__ out1) {
  extern __shared__ __align__(16) __bf16 smem[];
  __bf16* sA = smem;
  __bf16* sB = smem + 32768;

  const int lid = blockIdx.x + 16 * (blockIdx.y + 8 * blockIdx.z);  // 0..255
  const int nid = (lid & 7) * 32 + (lid >> 3);
  const int bz = nid >> 7;          // k-half
  const int r_ = nid & 127;
  const int n0 = (r_ >> 4) * 256;
  const int m0 = (r_ & 15) * 256;
  float* dst = bz ? out1 : out0;
  const size_t kOff = (size_t)bz * (K2_ / 2);   // 6144

  const int t    = threadIdx.x;
  const int wave = t >> 6, lane = t & 63;
  const int wm = wave >> 2, wn = wave & 3;
  const int l4 = lane >> 4, r16 = lane & 15;
  const int LDK = K2_;

  const int rowSt = t >> 3;
  const int kcSt  = ((t & 7) ^ ((t >> 3) & 7)) << 3;
  const __bf16* aSrc = Ainter + (size_t)(m0 + rowSt) * K2_ + kOff + kcSt;
  const __bf16* bSrc = W      + (size_t)(n0 + rowSt) * K2_ + kOff + kcSt;
  __bf16* dA = sA + wave * 512;
  __bf16* dB = sB + wave * 512;

  const int kc0 = (l4 ^ (r16 & 7)) << 3;
  const int kc1 = ((4 + l4) ^ (r16 & 7)) << 3;
  const __bf16* pArd = sA + wm * 8192 + r16 * 64;
  const __bf16* pBrd = sB + (wn >> 1) * 8192 + ((wn & 1) * 64 + r16) * 64;

  floatx4 acc[8][4];
  #pragma unroll
  for (int mi = 0; mi < 8; ++mi)
    #pragma unroll
    for (int ni = 0; ni < 4; ++ni) {
      floatx4 z = {0.f, 0.f, 0.f, 0.f};
      acc[mi][ni] = z;
    }

  STG_B(0, 0); STG_B(0, 1); STG_A(0, 0); STG_A(0, 1);
  STG_B(1, 0); STG_B(1, 1);
  ASM_VMCNT(0);
  SBAR();

  const int NT = (K2_ / 2) / 64;   // 96
  for (int tt = 0; tt < NT - 1; ++tt) {
    TILE_BODY_STAGED(tt, NT);
  }
  TILE_BODY_LAST(NT - 1);

  const int rq = l4 * 4;
  #pragma unroll
  for (int mi = 0; mi < 8; ++mi) {
    const int rl = wm * 128 + mi * 16 + rq;
    #pragma unroll
    for (int ni = 0; ni < 4; ++ni) {
      const int cl = wn * 64 + ni * 16 + r16;
      #pragma unroll
      for (int r = 0; r < 4; ++r)
        dst[(size_t)(m0 + rl + r) * H_ + n0 + cl] = acc[mi][ni][r];
    }
  }
}

// -------- kernel 6: out += part (split-K reduction) ----------------------
__global__ void k_addout(float* __restrict__ out, const float* __restrict__ part) {
  size_t i = ((size_t)blockIdx.x * blockDim.x + threadIdx.x) * 4;
  float4 a = *(const float4*)(out + i);
  float4 b = *(const float4*)(part + i);
  a.x += b.x; a.y += b.y; a.z += b.z; a.w += b.w;
  *(float4*)(out + i) = a;
}

extern "C" void kernel_launch(void* const* d_in, const int* in_sizes, int n_in,
                              void* d_out, int out_size, void* d_ws, size_t ws_size,
                              hipStream_t stream) {
  const float* hs   = (const float*)d_in[0];   // [B,S,H]
  const float* rw   = (const float*)d_in[1];   // [T,E]
  const float* gup  = (const float*)d_in[2];   // [E,H,2I]
  const float* gups = (const float*)d_in[3];   // [E,H/128,2I/128]
  const float* dnp  = (const float*)d_in[4];   // [E,I,H]
  const float* dnps = (const float*)d_in[5];   // [E,I/128,H/128]
  float* out = (float*)d_out;                  // [T,H] fp32

  char* ws = (char*)d_ws;
  __bf16* hsb  = (__bf16*)ws;                          // 16 MiB: [T,H]
  __bf16* wgu  = (__bf16*)(ws + (size_t)(16 << 20));   // 96 MiB: [E,1536,H] interleaved
  __bf16* wdn  = (__bf16*)(ws + (size_t)(112 << 20));  // 48 MiB: [H, E*I] flat B^T
  __bf16* intr = (__bf16*)(ws + (size_t)(160 << 20));  // 96 MiB: [T, E*I]
  // part reuses the wgu region (dead after k_gemm1): 32 MiB fp32 [T,H]
  float* part = (float*)(ws + (size_t)(16 << 20));

  static int inited = 0;
  if (!inited) {
    hipFuncSetAttribute((const void*)k_gemm1,
                        hipFuncAttributeMaxDynamicSharedMemorySize, 132096);
    hipFuncSetAttribute((const void*)k_gemm2,
                        hipFuncAttributeMaxDynamicSharedMemorySize, 131072);
    inited = 1;
  }

  k_prep<<<4096 + 12288 + 6144, 256, 0, stream>>>(hs, hsb, gup, wgu, gups,
                                                  dnp, wdn, dnps);
  k_gemm1<<<dim3(T_ / 256, TWO_I / 256, E_), 512, 132096, stream>>>(hsb, wgu, rw, intr);
  k_gemm2<<<dim3(T_ / 256, H_ / 256, 2), 512, 131072, stream>>>(intr, wdn, out, part);
  k_addout<<<(T_ * H_) / (256 * 4), 256, 0, stream>>>(out, part);
}

// Round 5
// 905.032 us; speedup vs baseline: 1.1916x; 1.0151x over previous
//
#include <hip/hip_runtime.h>
#include <hip/hip_bf16.h>
#include <cstdint>

#define E_     16
#define H_     2048
#define I_     768
#define T_     4096
#define TWO_I  1536
#define K2_    (E_ * I_)   // 12288

typedef __bf16 bf16x8 __attribute__((ext_vector_type(8)));
typedef float  floatx4 __attribute__((ext_vector_type(4)));

__device__ __forceinline__ void gload_lds16(const void* g, void* l) {
  __builtin_amdgcn_global_load_lds(
      (const __attribute__((address_space(1))) void*)(void*)g,
      (__attribute__((address_space(3))) void*)l,
      16, 0, 0);
}

#define ASM_VMCNT(n) asm volatile("s_waitcnt vmcnt(" #n ")" ::: "memory")
#define ASM_LGKM0()  asm volatile("s_waitcnt lgkmcnt(0)" ::: "memory")
#define SBAR()       __builtin_amdgcn_s_barrier()
#define SCHED0()     __builtin_amdgcn_sched_barrier(0)
#define PRIO1()      __builtin_amdgcn_s_setprio(1)
#define PRIO0()      __builtin_amdgcn_s_setprio(0)

// ------------- kernel 1: fused convert + blockwise dequant/transpose -----
__device__ __forceinline__ void dq_body(const float* __restrict__ src,
                                        __bf16* __restrict__ dst,
                                        const float* __restrict__ scale,
                                        int e, int n0, int m0, int R, int C,
                                        size_t slab, size_t rowStride, int ilvHalf,
                                        float* tile) {
  const float s = scale[((size_t)e * (R >> 7) + (m0 >> 7)) * (C >> 7) + (n0 >> 7)];
  const float* sp = src + ((size_t)e * R + m0) * C + n0;
  const int t  = threadIdx.x;
  const int c4 = (t & 15) * 4;
  const int rb = t >> 4;
  #pragma unroll
  for (int p = 0; p < 4; ++p) {
    int r = p * 16 + rb;
    float4 v = *(const float4*)(sp + (size_t)r * C + c4);
    tile[(c4 + 0) * 65 + r] = v.x * s;
    tile[(c4 + 1) * 65 + r] = v.y * s;
    tile[(c4 + 2) * 65 + r] = v.z * s;
    tile[(c4 + 3) * 65 + r] = v.w * s;
  }
  __syncthreads();
  const int c8 = (t & 7) * 8;
  const int r0 = t >> 3;            // 0..31
  #pragma unroll
  for (int p = 0; p < 2; ++p) {
    int nr = r0 + p * 32;
    int ng = n0 + nr;
    int np;
    if (ilvHalf) {
      int h = (ng >= ilvHalf) ? 1 : 0;
      int iLoc = ng - h * ilvHalf;
      np = ((iLoc >> 5) << 6) + h * 32 + (iLoc & 31);
    } else {
      np = ng;
    }
    const float* row = &tile[nr * 65 + c8];
    bf16x8 o;
    #pragma unroll
    for (int j = 0; j < 8; ++j) o[j] = (__bf16)row[j];
    *(bf16x8*)(dst + (size_t)e * slab + (size_t)np * rowStride + m0 + c8) = o;
  }
}

__global__ void k_prep(const float* __restrict__ hs, __bf16* __restrict__ hsb,
                       const float* __restrict__ gup, __bf16* __restrict__ wgu,
                       const float* __restrict__ gups,
                       const float* __restrict__ dnp, __bf16* __restrict__ wdn,
                       const float* __restrict__ dnps) {
  __shared__ float tile[64 * 65];
  const int id = blockIdx.x;
  if (id < 4096) {
    size_t idx = ((size_t)id * blockDim.x + threadIdx.x) * 8;
    float4 a = *(const float4*)(hs + idx);
    float4 b = *(const float4*)(hs + idx + 4);
    bf16x8 o;
    o[0] = (__bf16)a.x; o[1] = (__bf16)a.y; o[2] = (__bf16)a.z; o[3] = (__bf16)a.w;
    o[4] = (__bf16)b.x; o[5] = (__bf16)b.y; o[6] = (__bf16)b.z; o[7] = (__bf16)b.w;
    *(bf16x8*)(hsb + idx) = o;
  } else if (id < 4096 + 12288) {
    const int id2 = id - 4096;
    const int bx = id2 % 24;
    const int rest = id2 / 24;
    const int by = rest & 31;
    const int e  = rest >> 5;
    dq_body(gup, wgu, gups, e, bx * 64, by * 64, H_, TWO_I,
            (size_t)TWO_I * H_, (size_t)H_, I_, tile);
  } else {
    const int id3 = id - (4096 + 12288);
    const int bx = id3 & 31;
    const int rest = id3 >> 5;
    const int by = rest % 12;
    const int e  = rest / 12;
    dq_body(dnp, wdn, dnps, e, bx * 64, by * 64, I_, H_,
            (size_t)I_, (size_t)K2_, 0, tile);
  }
}

// ================= 256x256 / BK=64 / 8-wave / 8-phase GEMM =================
// (R2 schedule: per-phase AF4 + LGKM0; measured best for this structure.)
#define STG_A(tt, h) do { int b_ = ((tt)&1)*16384 + (h)*8192; \
    gload_lds16(aSrc + (size_t)((h)*128)*LDK + (tt)*64, dA + b_); \
    gload_lds16(aSrc + (size_t)((h)*128 + 64)*LDK + (tt)*64, dA + b_ + 4096); } while (0)
#define STG_B(tt, h) do { int b_ = ((tt)&1)*16384 + (h)*8192; \
    gload_lds16(bSrc + (size_t)((h)*128)*LDK + (tt)*64, dB + b_); \
    gload_lds16(bSrc + (size_t)((h)*128 + 64)*LDK + (tt)*64, dB + b_ + 4096); } while (0)

#define AF4(MI0) do { \
    af[0][0] = *(const bf16x8*)(pA + (MI0)*1024 + kc0); \
    af[0][1] = *(const bf16x8*)(pA + (MI0)*1024 + kc1); \
    af[1][0] = *(const bf16x8*)(pA + ((MI0)+1)*1024 + kc0); \
    af[1][1] = *(const bf16x8*)(pA + ((MI0)+1)*1024 + kc1); } while (0)

#define BBLD() do { \
    _Pragma("unroll") \
    for (int ni = 0; ni < 4; ++ni) { \
      bb[ni][0] = *(const bf16x8*)(pB + ni * 1024 + kc0); \
      bb[ni][1] = *(const bf16x8*)(pB + ni * 1024 + kc1); \
    } } while (0)

#define MFMA16(MI0) do { \
    _Pragma("unroll") \
    for (int ii = 0; ii < 2; ++ii) { \
      _Pragma("unroll") \
      for (int ni = 0; ni < 4; ++ni) { \
        acc[(MI0)+ii][ni] = __builtin_amdgcn_mfma_f32_16x16x32_bf16(af[ii][0], bb[ni][0], acc[(MI0)+ii][ni], 0, 0, 0); \
        acc[(MI0)+ii][ni] = __builtin_amdgcn_mfma_f32_16x16x32_bf16(af[ii][1], bb[ni][1], acc[(MI0)+ii][ni], 0, 0, 0); \
      } \
    } } while (0)

#define PHASE(MI0, STAGE_STMT, CKPT_STMT) do { \
    AF4(MI0); \
    STAGE_STMT; \
    CKPT_STMT; \
    SBAR(); \
    ASM_LGKM0(); \
    SCHED0(); \
    PRIO1(); \
    MFMA16(MI0); \
    PRIO0(); \
    SBAR(); \
  } while (0)

#define TILE_BODY(tt, NT) do { \
    const int bo = ((tt) & 1) * 16384; \
    const __bf16* pA = pArd + bo; \
    const __bf16* pB = pBrd + bo; \
    bf16x8 bb[4][2], af[2][2]; \
    BBLD(); \
    PHASE(0, if ((tt) + 1 < (NT)) STG_A((tt) + 1, 0), (void)0); \
    PHASE(2, if ((tt) + 1 < (NT)) STG_A((tt) + 1, 1), (void)0); \
    PHASE(4, if ((tt) + 2 < (NT)) STG_B((tt) + 2, 0), (void)0); \
    PHASE(6, if ((tt) + 2 < (NT)) STG_B((tt) + 2, 1), \
             if ((tt) + 2 < (NT)) { ASM_VMCNT(4); } else { ASM_VMCNT(0); }); \
  } while (0)

// ---------------- kernel 4: per-expert GEMM1 + SiLU + rw ----------------
// Launched twice with eOff 0/8 (observability: two ~190 us dispatches so
// gemm2/prep surface in the top-5 counter rows). 768 blocks = 3/CU each.
__global__ __launch_bounds__(512, 2)
void k_gemm1(const __bf16* __restrict__ A, const __bf16* __restrict__ W,
             const float* __restrict__ rw, __bf16* __restrict__ inter,
             int eOff) {
  extern __shared__ __align__(16) __bf16 smem[];
  __bf16* sA = smem;              // 32768 elems (64 KiB)
  __bf16* sB = smem + 32768;      // 32768 elems (64 KiB)
  float*  sRW = (float*)(smem + 65536);  // 256 floats

  const int lid = blockIdx.x + 16 * (blockIdx.y + 6 * blockIdx.z);  // 0..767
  const int nid = (lid & 7) * 96 + (lid >> 3);                      // bijective
  const int e  = eOff + nid / 96;
  const int r_ = nid % 96;
  const int by = r_ >> 4;           // n-block 0..5
  const int m0 = (r_ & 15) * 256;
  const int n0 = by * 256;

  const int t    = threadIdx.x;
  const int wave = t >> 6, lane = t & 63;
  const int wm = wave >> 2, wn = wave & 3;
  const int l4 = lane >> 4, r16 = lane & 15;
  const int LDK = H_;

  if (t < 256) sRW[t] = rw[(size_t)(m0 + t) * E_ + e];

  const int rowSt = t >> 3;
  const int kcSt  = ((t & 7) ^ ((t >> 3) & 7)) << 3;   // inverse swizzle on source
  const __bf16* aSrc = A + (size_t)(m0 + rowSt) * H_ + kcSt;
  const __bf16* bSrc = W + ((size_t)e * TWO_I + n0 + rowSt) * H_ + kcSt;
  __bf16* dA = sA + wave * 512;
  __bf16* dB = sB + wave * 512;

  const int kc0 = (l4 ^ (r16 & 7)) << 3;
  const int kc1 = ((4 + l4) ^ (r16 & 7)) << 3;
  const __bf16* pArd = sA + wm * 8192 + r16 * 64;
  const __bf16* pBrd = sB + (wn >> 1) * 8192 + ((wn & 1) * 64 + r16) * 64;

  floatx4 acc[8][4];
  #pragma unroll
  for (int mi = 0; mi < 8; ++mi)
    #pragma unroll
    for (int ni = 0; ni < 4; ++ni) {
      floatx4 z = {0.f, 0.f, 0.f, 0.f};
      acc[mi][ni] = z;
    }

  // prologue: hard-drain so every wave sees B(0),A(0),B(1) resident at barrier
  STG_B(0, 0); STG_B(0, 1); STG_A(0, 0); STG_A(0, 1);
  STG_B(1, 0); STG_B(1, 1);
  ASM_VMCNT(0);
  SBAR();

  const int NT = H_ / 64;   // 32
  for (int tt = 0; tt < NT; ++tt) {
    TILE_BODY(tt, NT);
  }

  // epilogue: ni in {0,1} = gate rows, ni+2 = up rows of the SAME i-range
  const int rq = l4 * 4;
  const int gBase = (by * 4 + wn) * 32;
  #pragma unroll
  for (int mi = 0; mi < 8; ++mi) {
    const int rl = wm * 128 + mi * 16 + rq;
    #pragma unroll
    for (int ni = 0; ni < 2; ++ni) {
      const size_t colIdx = (size_t)e * I_ + gBase + ni * 16 + r16;
      #pragma unroll
      for (int r = 0; r < 4; ++r) {
        float g = acc[mi][ni][r];
        float u = acc[mi][ni + 2][r];
        float sil = g / (1.0f + __expf(-g));
        float val = u * sil * sRW[rl + r];
        inter[(size_t)(m0 + rl + r) * K2_ + colIdx] = (__bf16)val;
      }
    }
  }
}

// -------- kernel 5: flat GEMM2, K = E*I, split-K=2, two buffers ----------
__global__ __launch_bounds__(512, 2)
void k_gemm2(const __bf16* __restrict__ Ainter, const __bf16* __restrict__ W,
             float* __restrict__ out0, float* __restrict__ out1) {
  extern __shared__ __align__(16) __bf16 smem[];
  __bf16* sA = smem;
  __bf16* sB = smem + 32768;

  const int lid = blockIdx.x + 16 * (blockIdx.y + 8 * blockIdx.z);  // 0..255
  const int nid = (lid & 7) * 32 + (lid >> 3);
  const int bz = nid >> 7;          // k-half
  const int r_ = nid & 127;
  const int n0 = (r_ >> 4) * 256;
  const int m0 = (r_ & 15) * 256;
  float* dst = bz ? out1 : out0;
  const size_t kOff = (size_t)bz * (K2_ / 2);   // 6144

  const int t    = threadIdx.x;
  const int wave = t >> 6, lane = t & 63;
  const int wm = wave >> 2, wn = wave & 3;
  const int l4 = lane >> 4, r16 = lane & 15;
  const int LDK = K2_;

  const int rowSt = t >> 3;
  const int kcSt  = ((t & 7) ^ ((t >> 3) & 7)) << 3;
  const __bf16* aSrc = Ainter + (size_t)(m0 + rowSt) * K2_ + kOff + kcSt;
  const __bf16* bSrc = W      + (size_t)(n0 + rowSt) * K2_ + kOff + kcSt;
  __bf16* dA = sA + wave * 512;
  __bf16* dB = sB + wave * 512;

  const int kc0 = (l4 ^ (r16 & 7)) << 3;
  const int kc1 = ((4 + l4) ^ (r16 & 7)) << 3;
  const __bf16* pArd = sA + wm * 8192 + r16 * 64;
  const __bf16* pBrd = sB + (wn >> 1) * 8192 + ((wn & 1) * 64 + r16) * 64;

  floatx4 acc[8][4];
  #pragma unroll
  for (int mi = 0; mi < 8; ++mi)
    #pragma unroll
    for (int ni = 0; ni < 4; ++ni) {
      floatx4 z = {0.f, 0.f, 0.f, 0.f};
      acc[mi][ni] = z;
    }

  STG_B(0, 0); STG_B(0, 1); STG_A(0, 0); STG_A(0, 1);
  STG_B(1, 0); STG_B(1, 1);
  ASM_VMCNT(0);
  SBAR();

  const int NT = (K2_ / 2) / 64;   // 96
  for (int tt = 0; tt < NT; ++tt) {
    TILE_BODY(tt, NT);
  }

  const int rq = l4 * 4;
  #pragma unroll
  for (int mi = 0; mi < 8; ++mi) {
    const int rl = wm * 128 + mi * 16 + rq;
    #pragma unroll
    for (int ni = 0; ni < 4; ++ni) {
      const int cl = wn * 64 + ni * 16 + r16;
      #pragma unroll
      for (int r = 0; r < 4; ++r)
        dst[(size_t)(m0 + rl + r) * H_ + n0 + cl] = acc[mi][ni][r];
    }
  }
}

// -------- kernel 6: out += part (split-K reduction) ----------------------
__global__ void k_addout(float* __restrict__ out, const float* __restrict__ part) {
  size_t i = ((size_t)blockIdx.x * blockDim.x + threadIdx.x) * 4;
  float4 a = *(const float4*)(out + i);
  float4 b = *(const float4*)(part + i);
  a.x += b.x; a.y += b.y; a.z += b.z; a.w += b.w;
  *(float4*)(out + i) = a;
}

extern "C" void kernel_launch(void* const* d_in, const int* in_sizes, int n_in,
                              void* d_out, int out_size, void* d_ws, size_t ws_size,
                              hipStream_t stream) {
  const float* hs   = (const float*)d_in[0];   // [B,S,H]
  const float* rw   = (const float*)d_in[1];   // [T,E]
  const float* gup  = (const float*)d_in[2];   // [E,H,2I]
  const float* gups = (const float*)d_in[3];   // [E,H/128,2I/128]
  const float* dnp  = (const float*)d_in[4];   // [E,I,H]
  const float* dnps = (const float*)d_in[5];   // [E,I/128,H/128]
  float* out = (float*)d_out;                  // [T,H] fp32

  char* ws = (char*)d_ws;
  __bf16* hsb  = (__bf16*)ws;                          // 16 MiB: [T,H]
  __bf16* wgu  = (__bf16*)(ws + (size_t)(16 << 20));   // 96 MiB: [E,1536,H] interleaved
  __bf16* wdn  = (__bf16*)(ws + (size_t)(112 << 20));  // 48 MiB: [H, E*I] flat B^T
  __bf16* intr = (__bf16*)(ws + (size_t)(160 << 20));  // 96 MiB: [T, E*I]
  // part reuses the wgu region (dead after k_gemm1): 32 MiB fp32 [T,H]
  float* part = (float*)(ws + (size_t)(16 << 20));

  static int inited = 0;
  if (!inited) {
    hipFuncSetAttribute((const void*)k_gemm1,
                        hipFuncAttributeMaxDynamicSharedMemorySize, 132096);
    hipFuncSetAttribute((const void*)k_gemm2,
                        hipFuncAttributeMaxDynamicSharedMemorySize, 131072);
    inited = 1;
  }

  k_prep<<<4096 + 12288 + 6144, 256, 0, stream>>>(hs, hsb, gup, wgu, gups,
                                                  dnp, wdn, dnps);
  k_gemm1<<<dim3(16, 6, 8), 512, 132096, stream>>>(hsb, wgu, rw, intr, 0);
  k_gemm1<<<dim3(16, 6, 8), 512, 132096, stream>>>(hsb, wgu, rw, intr, 8);
  k_gemm2<<<dim3(T_ / 256, H_ / 256, 2), 512, 131072, stream>>>(intr, wdn, out, part);
  k_addout<<<(T_ * H_) / (256 * 4), 256, 0, stream>>>(out, part);
}